// Round 10
// baseline (331.857 us; speedup 1.0000x reference)
//
#include <hip/hip_runtime.h>

typedef __attribute__((ext_vector_type(8))) short short8;
typedef __attribute__((ext_vector_type(4))) float f32x4;

#define DIM  1024
#define BT   8192   // B * TGT rows
#define NBAT 8

__device__ __forceinline__ unsigned short f2bf(float x){
  union { float f; unsigned u; } un; un.f = x;
  unsigned r = un.u + 0x7fffu + ((un.u >> 16) & 1u);   // round-to-nearest-even
  return (unsigned short)(r >> 16);
}
__device__ __forceinline__ float bf2f(unsigned short h){
  union { unsigned u; float f; } un; un.u = ((unsigned)h) << 16;
  return un.f;
}

// split f32 -> hi/lo bf16
__global__ void split_kernel(const float* __restrict__ x,
                             unsigned short* __restrict__ hi,
                             unsigned short* __restrict__ lo,
                             int n4){
  int stride = gridDim.x * blockDim.x;
  for (int i = blockIdx.x * blockDim.x + threadIdx.x; i < n4; i += stride){
    float4 v = ((const float4*)x)[i];
    ushort4 h, l;
    h.x = f2bf(v.x); l.x = f2bf(v.x - bf2f(h.x));
    h.y = f2bf(v.y); l.y = f2bf(v.y - bf2f(h.y));
    h.z = f2bf(v.z); l.z = f2bf(v.z - bf2f(h.z));
    h.w = f2bf(v.w); l.w = f2bf(v.w - bf2f(h.w));
    ((ushort4*)hi)[i] = h;
    ((ushort4*)lo)[i] = l;
  }
}

// plain f32 -> bf16 convert (Wout: lo term no longer used by GEMM4)
__global__ void cvt_kernel(const float* __restrict__ x,
                           unsigned short* __restrict__ hi, int n4){
  int stride = gridDim.x * blockDim.x;
  for (int i = blockIdx.x * blockDim.x + threadIdx.x; i < n4; i += stride){
    float4 v = ((const float4*)x)[i];
    ushort4 h;
    h.x = f2bf(v.x); h.y = f2bf(v.y); h.z = f2bf(v.z); h.w = f2bf(v.w);
    ((ushort4*)hi)[i] = h;
  }
}

// fused: context [b][s][d] f32 -> cx_hi/cx_lo [b][s][d] bf16 + ctxT [b][d][s]
// bf16 (hi).  Single read of context (was: split pass + transpose pass).
__global__ void ctx_prep_kernel(const float* __restrict__ ctx,
                                unsigned short* __restrict__ hi,
                                unsigned short* __restrict__ lo,
                                unsigned short* __restrict__ ctxT){
  __shared__ unsigned short t[64][65];
  int bz = blockIdx.z;
  int s0 = blockIdx.x << 6, d0 = blockIdx.y << 6;
  int tx = threadIdx.x, ty = threadIdx.y;   // (64,4)
  const size_t base = (((size_t)bz << 10) + s0) * DIM + d0;
  const float* src = ctx + base;
  unsigned short* hrow = hi + base;
  unsigned short* lrow = lo + base;
  #pragma unroll
  for (int i = ty; i < 64; i += 4){
    float v = src[(size_t)i * DIM + tx];
    unsigned short h = f2bf(v);
    hrow[(size_t)i * DIM + tx] = h;
    lrow[(size_t)i * DIM + tx] = f2bf(v - bf2f(h));
    t[i][tx] = h;
  }
  __syncthreads();
  unsigned short* dst = ctxT + (((size_t)bz << 10) + d0) * DIM + s0;
  #pragma unroll
  for (int i = ty; i < 64; i += 4)
    dst[(size_t)i * DIM + tx] = t[tx][i];
}

// masked softmax over rows of 1024; writes P f32 back in place (d_out align
// region) and P bf16 to Pb for the PV GEMM. One 256-thread block per row.
// Fully-masked words (s0 >= len) are not loaded (they'd be replaced by -inf
// anyway) -> saves ~44% of the score read traffic; output bit-identical.
__global__ __launch_bounds__(256) void softmax_kernel(float* __restrict__ sc,
                                                      unsigned short* __restrict__ Pb,
                                                      const int* __restrict__ lens){
  const int row = blockIdx.x;
  const int len = lens[row >> 10];
  const int tid = threadIdx.x;
  const int lane = tid & 63, wid = tid >> 6;
  float* rp = sc + ((size_t)row << 10);
  const int s0 = tid << 2;
  float4 v;
  if (s0 < len) v = ((const float4*)rp)[tid];
  else          v = (float4){0.f, 0.f, 0.f, 0.f};
  float x0 = (s0 + 0 < len) ? v.x : -INFINITY;
  float x1 = (s0 + 1 < len) ? v.y : -INFINITY;
  float x2 = (s0 + 2 < len) ? v.z : -INFINITY;
  float x3 = (s0 + 3 < len) ? v.w : -INFINITY;
  float wmax = fmaxf(fmaxf(x0, x1), fmaxf(x2, x3));
  #pragma unroll
  for (int o = 32; o > 0; o >>= 1) wmax = fmaxf(wmax, __shfl_xor(wmax, o));
  __shared__ float red[8];
  if (lane == 0) red[wid] = wmax;
  __syncthreads();
  float mx = fmaxf(fmaxf(red[0], red[1]), fmaxf(red[2], red[3]));
  float e0 = (s0 + 0 < len) ? __expf(x0 - mx) : 0.f;
  float e1 = (s0 + 1 < len) ? __expf(x1 - mx) : 0.f;
  float e2 = (s0 + 2 < len) ? __expf(x2 - mx) : 0.f;
  float e3 = (s0 + 3 < len) ? __expf(x3 - mx) : 0.f;
  float ws = e0 + e1 + e2 + e3;
  #pragma unroll
  for (int o = 32; o > 0; o >>= 1) ws += __shfl_xor(ws, o);
  if (lane == 0) red[4 + wid] = ws;
  __syncthreads();
  float inv = 1.f / (red[4] + red[5] + red[6] + red[7]);
  float4 p; p.x = e0 * inv; p.y = e1 * inv; p.z = e2 * inv; p.w = e3 * inv;
  ((float4*)rp)[tid] = p;
  ushort4 pb; pb.x = f2bf(p.x); pb.y = f2bf(p.y); pb.z = f2bf(p.z); pb.w = f2bf(p.w);
  ((ushort4*)(Pb + ((size_t)row << 10)))[tid] = pb;
}

// LDS layout for a Rx32 bf16 tile: element (r,k) at byte
//   r*64 + ((k>>3) ^ ((r>>1)&3))*16 + (k&7)*2
// -> ds_read_b128 fragment reads are 2-way (free) instead of 8-way conflicts.
__device__ __forceinline__ int lds_off(int r, int kb){
  return r * 64 + (((kb ^ ((r >> 1) & 3))) << 4);
}

// ---------------------------------------------------------------------------
// Pipelined 256x128 GEMM (GEMM1 / GEMM4): C = A @ B^T, f32 accum.
// SM=0: full split, 3 MFMAs/k (hh+hl+lh).   SM=2: pure bf16, 1 MFMA/k.
// BREG=1: B operand NEVER touches LDS -- per-lane fragments loaded directly
// from global (B is L2-resident: Win/Wout <= 4MB/XCD).  Cuts LDS ops/step
// 22->12 (SM0) and 11->6 (SM2).  Empirical law (R6/R8/R9): time tracks
// LDS-op count linearly, so this is the validated lever.
// B regs double-buffered (bh/bl = cur, bhn/bln = nxt): B(t+1) issued at top
// of step t, copied to cur at top of step t+1 -- full-step latency window.
// vmcnt ledger (BREG): per step issue B(t+1)[b] then A-stage(t+2)[a];
// end-of-step vmcnt(a) retires exactly A(t+1)+B(t+1) (oldest a+b).
// 8 waves of 64x64; triple-buffered A; 4 fine phases/K-step.
// ---------------------------------------------------------------------------
#define TILEA 16384                       // 256 rows x 64 B
#define TILEB 8192                        // 128 rows x 64 B

__device__ __forceinline__ void gld16(void* lds, const void* g){
  __builtin_amdgcn_global_load_lds(
      (__attribute__((address_space(1))) void*)(g),
      (__attribute__((address_space(3))) void*)(lds), 16, 0, 0);
}

// EPI: 0 = write hi/lo bf16 split (o1,o2);  3 = write tanhf(x) f32 (outF)
// NT:  number of K-tiles (K = NT*32), compile-time.
// KSPLIT: A columns >= KSPLIT come from Ah2/Al2 (set KSPLIT = NT*32 to disable)
template<int EPI, int NT, int KSPLIT, int SM, int BREG>
__global__ __launch_bounds__(512, 2) void gemm_pipe_kernel(
    const unsigned short* __restrict__ Ah,  const unsigned short* __restrict__ Al,
    const unsigned short* __restrict__ Ah2, const unsigned short* __restrict__ Al2,
    const unsigned short* __restrict__ Bh,  const unsigned short* __restrict__ Bl,
    int lda, int ldb,
    float* __restrict__ outF, unsigned short* __restrict__ o1,
    unsigned short* __restrict__ o2, int ldo)
{
  constexpr int OFF_AL = TILEA;                         // SM0 only
  constexpr int OFF_BH = (SM == 0) ? 2 * TILEA : TILEA;
  constexpr int OFF_BL = OFF_BH + TILEB;                // SM0/SM1 only
  constexpr int BUFSZ_T =
      BREG ? ((SM == 0) ? 2 * TILEA : TILEA)            // A only in LDS
           : ((SM == 2) ? (OFF_BH + TILEB) : (OFF_BL + TILEB));

  __shared__ __align__(16) char sm0[BUFSZ_T];
  __shared__ __align__(16) char sm1[BUFSZ_T];
  __shared__ __align__(16) char sm2[BUFSZ_T];

  const int tid  = threadIdx.x;
  const int lane = tid & 63;
  const int w    = tid >> 6;

  int bx = blockIdx.x, by = blockIdx.y;
  { // XCD swizzle: each XCD owns a compact (gridDim.y/8)-row x 8-col chunk
    int o = bx + (by << 3);
    int xcd = o & 7, j = o >> 3;
    bx = j & 7;
    by = xcd * (gridDim.y >> 3) + (j >> 3);
  }
  const int m0 = by << 8;
  const int n0 = bx << 7;

  const unsigned short* gAh  = Ah  + (size_t)m0 * lda;
  const unsigned short* gAl  = Al  + (size_t)m0 * lda;
  const unsigned short* gAh2 = Ah2 + (size_t)m0 * lda;
  const unsigned short* gAl2 = Al2 + (size_t)m0 * lda;
  const unsigned short* gBh  = Bh  + (size_t)n0 * ldb;
  const unsigned short* gBl  = Bl  + (size_t)n0 * ldb;

  const int wr = (w >> 1) << 6;
  const int wc = (w & 1) << 6;
  const int fr = lane & 15;
  const int kb = lane >> 4;

  // A staging: lane l covers row r0+(l>>2), PHYSICAL 16B chunk (l&3); global
  // source is LOGICAL chunk (l&3)^((r>>1)&3) (XOR involution; read side uses
  // lds_off with the same XOR -> both-sides swizzle, rule 21).
  const int rA0 = (w << 5) + (lane >> 2);
  const int rA1 = rA0 + 16;
  const int rB0 = (w << 4) + (lane >> 2);
  const int cA0 = ((lane & 3) ^ ((rA0 >> 1) & 3)) << 3;   // element offset
  const int cA1 = ((lane & 3) ^ ((rA1 >> 1) & 3)) << 3;
  const int cB0 = ((lane & 3) ^ ((rB0 >> 1) & 3)) << 3;
  const unsigned short* pAh0  = gAh  + (size_t)rA0 * lda + cA0;
  const unsigned short* pAh1  = gAh  + (size_t)rA1 * lda + cA1;
  const unsigned short* pAl0  = gAl  + (size_t)rA0 * lda + cA0;
  const unsigned short* pAl1  = gAl  + (size_t)rA1 * lda + cA1;
  const unsigned short* pAh20 = gAh2 + (size_t)rA0 * lda + cA0;
  const unsigned short* pAh21 = gAh2 + (size_t)rA1 * lda + cA1;
  const unsigned short* pAl20 = gAl2 + (size_t)rA0 * lda + cA0;
  const unsigned short* pAl21 = gAl2 + (size_t)rA1 * lda + cA1;
  const unsigned short* pBh0  = gBh  + (size_t)rB0 * ldb + cB0;   // !BREG
  const unsigned short* pBl0  = gBl  + (size_t)rB0 * ldb + cB0;   // !BREG
  const int dA0 = (w << 5) << 6;          // wave-uniform LDS byte offsets
  const int dA1 = dA0 + (16 << 6);
  const int dB0 = (w << 4) << 6;
  (void)pBh0; (void)pBl0; (void)dB0;

  // BREG: per-lane B fragment pointers (UNSWIZZLED -- straight from global).
  // fragment (n): row = wc + n*16 + fr, k-chunk = kb*8 within the k0 window.
  const unsigned short* pBfh[4];
  const unsigned short* pBfl[4];
  if constexpr (BREG){
    #pragma unroll
    for (int n = 0; n < 4; n++){
      size_t roff = (size_t)(wc + n * 16 + fr) * ldb + kb * 8;
      pBfh[n] = gBh + roff;
      pBfl[n] = gBl + roff;
    }
  }

  f32x4 acc[4][4];
  #pragma unroll
  for (int m = 0; m < 4; m++)
    #pragma unroll
    for (int n = 0; n < 4; n++)
      acc[m][n] = (f32x4){0.f, 0.f, 0.f, 0.f};

  short8 ah, al, bh[4], bl[4], bhn[4], bln[4];

#define STAGE(WR, KS) do { int _k = (KS);                                   \
    const unsigned short *_s0, *_s1;                                        \
    if (KSPLIT < NT * 32 && _k >= KSPLIT){                                  \
      int _q = _k - KSPLIT;                                                 \
      _s0 = pAh20 + _q; _s1 = pAh21 + _q;                                   \
    } else { _s0 = pAh0 + _k; _s1 = pAh1 + _k; }                            \
    gld16(WR + dA0, _s0);                                                   \
    gld16(WR + dA1, _s1);                                                   \
    if constexpr (SM == 0){                                                 \
      const unsigned short *_s2, *_s3;                                      \
      if (KSPLIT < NT * 32 && _k >= KSPLIT){                                \
        int _q = _k - KSPLIT;                                               \
        _s2 = pAl20 + _q; _s3 = pAl21 + _q;                                 \
      } else { _s2 = pAl0 + _k; _s3 = pAl1 + _k; }                          \
      gld16(WR + OFF_AL + dA0, _s2);                                        \
      gld16(WR + OFF_AL + dA1, _s3);                                        \
    }                                                                       \
    if constexpr (!BREG){                                                   \
      gld16(WR + OFF_BH + dB0, pBh0 + _k);                                  \
      if constexpr (SM != 2)                                                \
        gld16(WR + OFF_BL + dB0, pBl0 + _k);                                \
    }                                                                       \
  } while(0)

#define LOAD_B_NXT(T1) do { int _kb2 = (T1) << 5;                           \
    _Pragma("unroll")                                                       \
    for (int n = 0; n < 4; n++){                                            \
      bhn[n] = *(const short8*)(pBfh[n] + _kb2);                            \
      if constexpr (SM != 2) bln[n] = *(const short8*)(pBfl[n] + _kb2);     \
    }                                                                       \
  } while(0)

#define COPY_B() do {                                                       \
    _Pragma("unroll")                                                       \
    for (int n = 0; n < 4; n++){                                            \
      bh[n] = bhn[n];                                                       \
      if constexpr (SM != 2) bl[n] = bln[n];                                \
    }                                                                       \
  } while(0)

#define READS_B(RD) do {                                                    \
    _Pragma("unroll")                                                       \
    for (int n = 0; n < 4; n++){                                            \
      int off = lds_off(wc + n * 16 + fr, kb);                              \
      bh[n] = *(const short8*)((RD) + OFF_BH + off);                        \
      if constexpr (SM != 2)                                                \
        bl[n] = *(const short8*)((RD) + OFF_BL + off);                      \
    }                                                                       \
  } while(0)

#define READS_A(RD, M) do {                                                 \
    int off = lds_off(wr + (M) * 16 + fr, kb);                              \
    ah = *(const short8*)((RD) + off);                                      \
    if constexpr (SM == 0) al = *(const short8*)((RD) + OFF_AL + off);      \
  } while(0)

#define MFMA_M(M) do {                                                      \
    __builtin_amdgcn_s_setprio(1);                                          \
    _Pragma("unroll")                                                       \
    for (int n = 0; n < 4; n++){                                            \
      acc[M][n] = __builtin_amdgcn_mfma_f32_16x16x32_bf16(ah, bh[n], acc[M][n], 0, 0, 0); \
      if constexpr (SM != 2)                                                \
        acc[M][n] = __builtin_amdgcn_mfma_f32_16x16x32_bf16(ah, bl[n], acc[M][n], 0, 0, 0); \
      if constexpr (SM == 0)                                                \
        acc[M][n] = __builtin_amdgcn_mfma_f32_16x16x32_bf16(al, bh[n], acc[M][n], 0, 0, 0); \
    }                                                                       \
    __builtin_amdgcn_s_setprio(0);                                          \
  } while(0)

#define BAR() do { __builtin_amdgcn_s_barrier();                            \
                   asm volatile("" ::: "memory"); } while(0)
#define LGKM0() asm volatile("s_waitcnt lgkmcnt(0)" ::: "memory")
// BREG: retire A(t+1)+B(t+1), leave A(t+2) [a in flight].  a = stage count.
#define VMCNT_STEP() do {                                                   \
    if constexpr (BREG){                                                    \
      if constexpr (SM == 0) asm volatile("s_waitcnt vmcnt(4)" ::: "memory"); \
      else                   asm volatile("s_waitcnt vmcnt(2)" ::: "memory"); \
    } else if constexpr (SM == 0) asm volatile("s_waitcnt vmcnt(6)" ::: "memory"); \
    else if constexpr (SM == 1)   asm volatile("s_waitcnt vmcnt(4)" ::: "memory"); \
    else                          asm volatile("s_waitcnt vmcnt(3)" ::: "memory"); \
  } while(0)

// one K-step: 4 fine phases; ds_reads issued before each barrier; one counted
// vmcnt per step boundary.
#define STEP(RD, WR, T) do {                                                \
    int _ks = (((T) + 2 < NT) ? (T) + 2 : NT - 1) << 5;  /* dead-stage clamp */ \
    if constexpr (BREG){                                                    \
      COPY_B();                                                             \
      LOAD_B_NXT((((T) + 1 < NT) ? (T) + 1 : NT - 1));                      \
    } else {                                                                \
      READS_B(RD);                                                          \
    }                                                                       \
    READS_A(RD, 0);                                                         \
    STAGE(WR, _ks);                                                         \
    BAR(); LGKM0(); MFMA_M(0); BAR();                                       \
    READS_A(RD, 1);                                                        \
    BAR(); LGKM0(); MFMA_M(1); BAR();                                       \
    READS_A(RD, 2);                                                        \
    BAR(); LGKM0(); MFMA_M(2); BAR();                                       \
    READS_A(RD, 3);                                                        \
    BAR(); LGKM0(); MFMA_M(3);                                              \
    VMCNT_STEP();                                                           \
    BAR();                                                                  \
  } while(0)

  if constexpr (BREG){
    STAGE(sm0, 0);        // A(0) [a]
    LOAD_B_NXT(0);        // B(0) [b] -> nxt (copied to cur at step 0 top)
    STAGE(sm1, 32);       // A(1) [a]
    VMCNT_STEP();         // vmcnt(a): retires A(0)+B(0), leaves A(1)
    BAR();
  } else {
    STAGE(sm0, 0);
    STAGE(sm1, 32);
    VMCNT_STEP();
    BAR();
  }

  for (int t = 0; t < NT; t += 3){
    STEP(sm0, sm2, t);
    if (t + 1 < NT) STEP(sm1, sm0, t + 1);
    if (t + 2 < NT) STEP(sm2, sm1, t + 2);
  }
#undef STAGE
#undef LOAD_B_NXT
#undef COPY_B
#undef READS_B
#undef READS_A
#undef MFMA_M
#undef BAR
#undef LGKM0
#undef VMCNT_STEP
#undef STEP

  // epilogue: C/D layout col = lane&15, row = (lane>>4)*4 + reg  [m89-verified]
  const int rbase = (lane >> 4) << 2;
  const int cbase = lane & 15;
  #pragma unroll
  for (int m = 0; m < 4; m++){
    #pragma unroll
    for (int n = 0; n < 4; n++){
      f32x4 v = acc[m][n];
      int col = n0 + wc + n * 16 + cbase;
      #pragma unroll
      for (int j = 0; j < 4; j++){
        int row = m0 + wr + m * 16 + rbase + j;
        float val = v[j];
        size_t idx = (size_t)row * ldo + col;
        if (EPI == 0){
          unsigned short h = f2bf(val);
          o1[idx] = h;
          o2[idx] = f2bf(val - bf2f(h));
        } else {
          outF[idx] = tanhf(val);
        }
      }
    }
  }
}

// ---------------------------------------------------------------------------
// Proven 128^2 kernel for the batched GEMMs (len-skip / len-clamp).
// EPI: 0 = split bf16 out; 1 = f32 out; 3 = tanh f32 out; 4 = bf16 out.
// ---------------------------------------------------------------------------
template<bool SPLIT, int EPI>
__global__ __launch_bounds__(256, 2) void gemm_kernel(
    const unsigned short* __restrict__ Ah, const unsigned short* __restrict__ Al,
    const unsigned short* __restrict__ Bh, const unsigned short* __restrict__ Bl,
    int K, int lda, int ldb,
    long long aStride, long long bStride, long long oStride,
    float* __restrict__ outF, unsigned short* __restrict__ o1,
    unsigned short* __restrict__ o2, int ldo,
    const int* __restrict__ lens, int lmode)
{
  constexpr int TILE = 128 * 64;  // bytes per staged tile
  __shared__ char smem[(SPLIT ? 4 : 2) * TILE];
  char* sAh = smem;
  char* sBh = smem + TILE;
  char* sAl = smem + (SPLIT ? 2 : 0) * TILE;
  char* sBl = smem + (SPLIT ? 3 : 0) * TILE;

  const int tid  = threadIdx.x;
  const int lane = tid & 63;
  const int wid  = tid >> 6;
  const int z    = blockIdx.z;

  int bx = blockIdx.x, by = blockIdx.y;
  if (gridDim.x == 8 && gridDim.y == 8){
    int o = bx + (by << 3);
    int k = o & 7, j = o >> 3;
    bx = ((k & 3) << 1) | (j & 1);  by = ((k >> 2) << 2) | (j >> 1);
  }
  const int m0 = by * 128;
  const int n0 = bx * 128;

  int Keff = K;
  if (lmode){
    const int len = lens[z];
    if (lmode == 1 && n0 >= len) return;       // output fully masked downstream
    if (lmode == 2){
      int kc = (len + 31) & ~31;
      Keff = kc < K ? kc : K;                  // P is exactly 0 beyond len
    }
  }

  const unsigned short* gAh = Ah + (size_t)z * aStride + (size_t)m0 * lda;
  const unsigned short* gBh = Bh + (size_t)z * bStride + (size_t)n0 * ldb;
  const unsigned short* gAl = SPLIT ? (Al + (size_t)z * aStride + (size_t)m0 * lda) : (const unsigned short*)0;
  const unsigned short* gBl = SPLIT ? (Bl + (size_t)z * bStride + (size_t)n0 * ldb) : (const unsigned short*)0;

  f32x4 acc[4][4];
  #pragma unroll
  for (int m = 0; m < 4; m++)
    #pragma unroll
    for (int n = 0; n < 4; n++)
      acc[m][n] = (f32x4){0.f, 0.f, 0.f, 0.f};

  const int wr = (wid >> 1) * 64;
  const int wc = (wid & 1) * 64;
  const int fr = lane & 15;
  const int kb = lane >> 4;

  for (int k0 = 0; k0 < Keff; k0 += 32){
    __syncthreads();
    #pragma unroll
    for (int it = 0; it < 2; ++it){
      int c = tid + it * 256;
      int r = c >> 2, kk = c & 3;
      int lo = lds_off(r, kk);
      size_t ga = (size_t)r * lda + k0 + kk * 8;
      size_t gb = (size_t)r * ldb + k0 + kk * 8;
      *(short8*)(sAh + lo) = *(const short8*)(gAh + ga);
      *(short8*)(sBh + lo) = *(const short8*)(gBh + gb);
      if (SPLIT){
        *(short8*)(sAl + lo) = *(const short8*)(gAl + ga);
        *(short8*)(sBl + lo) = *(const short8*)(gBl + gb);
      }
    }
    __syncthreads();

    short8 ah[4], bh[4], al[4], bl[4];
    #pragma unroll
    for (int m = 0; m < 4; m++){
      int off = lds_off(wr + m * 16 + fr, kb);
      ah[m] = *(const short8*)(sAh + off);
      if (SPLIT) al[m] = *(const short8*)(sAl + off);
    }
    #pragma unroll
    for (int n = 0; n < 4; n++){
      int off = lds_off(wc + n * 16 + fr, kb);
      bh[n] = *(const short8*)(sBh + off);
      if (SPLIT) bl[n] = *(const short8*)(sBl + off);
    }
    #pragma unroll
    for (int m = 0; m < 4; m++)
      #pragma unroll
      for (int n = 0; n < 4; n++){
        acc[m][n] = __builtin_amdgcn_mfma_f32_16x16x32_bf16(ah[m], bh[n], acc[m][n], 0, 0, 0);
        if (SPLIT){
          acc[m][n] = __builtin_amdgcn_mfma_f32_16x16x32_bf16(ah[m], bl[n], acc[m][n], 0, 0, 0);
          acc[m][n] = __builtin_amdgcn_mfma_f32_16x16x32_bf16(al[m], bh[n], acc[m][n], 0, 0, 0);
        }
      }
  }

  const int rbase = (lane >> 4) * 2 * 2;
  const int cbase = lane & 15;
  #pragma unroll
  for (int m = 0; m < 4; m++){
    #pragma unroll
    for (int n = 0; n < 4; n++){
      f32x4 v = acc[m][n];
      int col = n0 + wc + n * 16 + cbase;
      #pragma unroll
      for (int j = 0; j < 4; j++){
        int row = m0 + wr + m * 16 + rbase + j;
        float val = v[j];
        size_t idx = (size_t)row * ldo + col;
        if (EPI == 0){
          unsigned short h = f2bf(val);
          o1[(size_t)z * oStride + idx] = h;
          o2[(size_t)z * oStride + idx] = f2bf(val - bf2f(h));
        } else if (EPI == 1){
          outF[(size_t)z * oStride + idx] = val;
        } else if (EPI == 4){
          o1[(size_t)z * oStride + idx] = f2bf(val);
        } else {
          outF[idx] = tanhf(val);
        }
      }
    }
  }
}

extern "C" void kernel_launch(void* const* d_in, const int* in_sizes, int n_in,
                              void* d_out, int out_size, void* d_ws, size_t ws_size,
                              hipStream_t stream){
  const float* input   = (const float*)d_in[0];
  const float* context = (const float*)d_in[1];
  const int*   lens    = (const int*)d_in[2];
  const float* Win     = (const float*)d_in[3];
  const float* Wout    = (const float*)d_in[4];
  float* attn  = (float*)d_out;
  float* align = attn + (size_t)BT * DIM;

  char* ws = (char*)d_ws;
  size_t off = 0;
  auto alloc = [&](size_t bytes) -> char* {
    char* p = ws + off; off += (bytes + 255) & ~(size_t)255; return p;
  };
  const size_t MTD = (size_t)BT * DIM;   // 8M elements
  unsigned short* in_hi = (unsigned short*)alloc(MTD * 2);
  unsigned short* in_lo = (unsigned short*)alloc(MTD * 2);
  unsigned short* cx_hi = (unsigned short*)alloc(MTD * 2);
  unsigned short* cx_lo = (unsigned short*)alloc(MTD * 2);
  unsigned short* wi_hi = (unsigned short*)alloc((size_t)DIM * DIM * 2);
  unsigned short* wi_lo = (unsigned short*)alloc((size_t)DIM * DIM * 2);
  unsigned short* ht_hi = (unsigned short*)alloc(MTD * 2);
  unsigned short* ht_lo = (unsigned short*)alloc(MTD * 2);
  unsigned short* cxT   = (unsigned short*)alloc(MTD * 2);
  unsigned short* c_hi  = (unsigned short*)alloc(MTD * 2);   // GEMM3 out (plain bf16)
  unsigned short* wo_hi = (unsigned short*)alloc((size_t)DIM * 2 * DIM * 2);
  unsigned short* p_bf  = cx_hi;   // alias: cx_hi dead after GEMM2
  if (off > ws_size) return;

  // prep: splits + W conversions + fused context split/transpose
  split_kernel<<<4096, 256, 0, stream>>>(input, in_hi, in_lo, (int)(MTD >> 2));
  split_kernel<<<1024, 256, 0, stream>>>(Win, wi_hi, wi_lo, (DIM * DIM) >> 2);
  cvt_kernel<<<2048, 256, 0, stream>>>(Wout, wo_hi, (DIM * 2 * DIM) >> 2);
  ctx_prep_kernel<<<dim3(16, 16, NBAT), dim3(64, 4), 0, stream>>>(context, cx_hi, cx_lo, cxT);

  // GEMM1: ht = input @ Win^T   (pipelined SM0 full split, B=Win in REGISTERS
  //        from L2 -- Win hi+lo = 4MB, L2-resident; LDS ops 22 -> 12)
  gemm_pipe_kernel<0, 32, 1024, 0, 1><<<dim3(8, 32), 512, 0, stream>>>(
      in_hi, in_lo, in_hi, in_lo, wi_hi, wi_lo, DIM, DIM,
      nullptr, ht_hi, ht_lo, DIM);
  // GEMM2: scores[b] = ht[b] @ ctx[b]^T  (split in, f32 out -> align region)
  gemm_kernel<true, 1><<<dim3(8, 8, NBAT), 256, 0, stream>>>(
      ht_hi, ht_lo, cx_hi, cx_lo, DIM, DIM, DIM,
      (long long)DIM * 1024, (long long)DIM * 1024, (long long)DIM * 1024,
      align, nullptr, nullptr, DIM, lens, 1);
  // masked softmax (in-place on align) + P bf16
  softmax_kernel<<<BT, 256, 0, stream>>>(align, p_bf, lens);
  // GEMM3: c[b] = P[b] @ ctxT[b]^T  (plain bf16 in, single bf16 out)
  gemm_kernel<false, 4><<<dim3(8, 8, NBAT), 256, 0, stream>>>(
      p_bf, nullptr, cxT, nullptr, DIM, DIM, DIM,
      (long long)DIM * 1024, (long long)DIM * 1024, (long long)1024 * 1024,
      nullptr, c_hi, nullptr, DIM, lens, 2);
  // GEMM4: attn = tanh([c | input] @ Wout^T)  (pipelined SM2 pure bf16,
  //        B=Wout-hi in REGISTERS from L2 (4MB); LDS ops 11 -> 6)
  gemm_pipe_kernel<3, 64, 1024, 2, 1><<<dim3(8, 32), 512, 0, stream>>>(
      c_hi, c_hi, in_hi, in_hi, wo_hi, wo_hi, DIM, 2 * DIM,
      attn, nullptr, nullptr, DIM);
}

// Round 11
// 228.456 us; speedup vs baseline: 1.4526x; 1.4526x over previous
//
#include <hip/hip_runtime.h>

typedef __attribute__((ext_vector_type(8))) short short8;
typedef __attribute__((ext_vector_type(4))) float f32x4;

#define DIM  1024
#define BT   8192   // B * TGT rows
#define NBAT 8

__device__ __forceinline__ unsigned short f2bf(float x){
  union { float f; unsigned u; } un; un.f = x;
  unsigned r = un.u + 0x7fffu + ((un.u >> 16) & 1u);   // round-to-nearest-even
  return (unsigned short)(r >> 16);
}
__device__ __forceinline__ float bf2f(unsigned short h){
  union { unsigned u; float f; } un; un.u = ((unsigned)h) << 16;
  return un.f;
}

// split f32 -> hi/lo bf16
__global__ void split_kernel(const float* __restrict__ x,
                             unsigned short* __restrict__ hi,
                             unsigned short* __restrict__ lo,
                             int n4){
  int stride = gridDim.x * blockDim.x;
  for (int i = blockIdx.x * blockDim.x + threadIdx.x; i < n4; i += stride){
    float4 v = ((const float4*)x)[i];
    ushort4 h, l;
    h.x = f2bf(v.x); l.x = f2bf(v.x - bf2f(h.x));
    h.y = f2bf(v.y); l.y = f2bf(v.y - bf2f(h.y));
    h.z = f2bf(v.z); l.z = f2bf(v.z - bf2f(h.z));
    h.w = f2bf(v.w); l.w = f2bf(v.w - bf2f(h.w));
    ((ushort4*)hi)[i] = h;
    ((ushort4*)lo)[i] = l;
  }
}

// plain f32 -> bf16 convert (Wout: lo term not used by GEMM4 SM2)
__global__ void cvt_kernel(const float* __restrict__ x,
                           unsigned short* __restrict__ hi, int n4){
  int stride = gridDim.x * blockDim.x;
  for (int i = blockIdx.x * blockDim.x + threadIdx.x; i < n4; i += stride){
    float4 v = ((const float4*)x)[i];
    ushort4 h;
    h.x = f2bf(v.x); h.y = f2bf(v.y); h.z = f2bf(v.z); h.w = f2bf(v.w);
    ((ushort4*)hi)[i] = h;
  }
}

// fused: context [b][s][d] f32 -> cx_hi/cx_lo [b][s][d] bf16 + ctxT [b][d][s]
// bf16 (hi).  Single read of context.
__global__ void ctx_prep_kernel(const float* __restrict__ ctx,
                                unsigned short* __restrict__ hi,
                                unsigned short* __restrict__ lo,
                                unsigned short* __restrict__ ctxT){
  __shared__ unsigned short t[64][65];
  int bz = blockIdx.z;
  int s0 = blockIdx.x << 6, d0 = blockIdx.y << 6;
  int tx = threadIdx.x, ty = threadIdx.y;   // (64,4)
  const size_t base = (((size_t)bz << 10) + s0) * DIM + d0;
  const float* src = ctx + base;
  unsigned short* hrow = hi + base;
  unsigned short* lrow = lo + base;
  #pragma unroll
  for (int i = ty; i < 64; i += 4){
    float v = src[(size_t)i * DIM + tx];
    unsigned short h = f2bf(v);
    hrow[(size_t)i * DIM + tx] = h;
    lrow[(size_t)i * DIM + tx] = f2bf(v - bf2f(h));
    t[i][tx] = h;
  }
  __syncthreads();
  unsigned short* dst = ctxT + (((size_t)bz << 10) + d0) * DIM + s0;
  #pragma unroll
  for (int i = ty; i < 64; i += 4)
    dst[(size_t)i * DIM + tx] = t[tx][i];
}

// masked softmax over rows of 1024; P f32 in place + P bf16 to Pb.
// Fully-masked words not loaded; output bit-identical.
__global__ __launch_bounds__(256) void softmax_kernel(float* __restrict__ sc,
                                                      unsigned short* __restrict__ Pb,
                                                      const int* __restrict__ lens){
  const int row = blockIdx.x;
  const int len = lens[row >> 10];
  const int tid = threadIdx.x;
  const int lane = tid & 63, wid = tid >> 6;
  float* rp = sc + ((size_t)row << 10);
  const int s0 = tid << 2;
  float4 v;
  if (s0 < len) v = ((const float4*)rp)[tid];
  else          v = (float4){0.f, 0.f, 0.f, 0.f};
  float x0 = (s0 + 0 < len) ? v.x : -INFINITY;
  float x1 = (s0 + 1 < len) ? v.y : -INFINITY;
  float x2 = (s0 + 2 < len) ? v.z : -INFINITY;
  float x3 = (s0 + 3 < len) ? v.w : -INFINITY;
  float wmax = fmaxf(fmaxf(x0, x1), fmaxf(x2, x3));
  #pragma unroll
  for (int o = 32; o > 0; o >>= 1) wmax = fmaxf(wmax, __shfl_xor(wmax, o));
  __shared__ float red[8];
  if (lane == 0) red[wid] = wmax;
  __syncthreads();
  float mx = fmaxf(fmaxf(red[0], red[1]), fmaxf(red[2], red[3]));
  float e0 = (s0 + 0 < len) ? __expf(x0 - mx) : 0.f;
  float e1 = (s0 + 1 < len) ? __expf(x1 - mx) : 0.f;
  float e2 = (s0 + 2 < len) ? __expf(x2 - mx) : 0.f;
  float e3 = (s0 + 3 < len) ? __expf(x3 - mx) : 0.f;
  float ws = e0 + e1 + e2 + e3;
  #pragma unroll
  for (int o = 32; o > 0; o >>= 1) ws += __shfl_xor(ws, o);
  if (lane == 0) red[4 + wid] = ws;
  __syncthreads();
  float inv = 1.f / (red[4] + red[5] + red[6] + red[7]);
  float4 p; p.x = e0 * inv; p.y = e1 * inv; p.z = e2 * inv; p.w = e3 * inv;
  ((float4*)rp)[tid] = p;
  ushort4 pb; pb.x = f2bf(p.x); pb.y = f2bf(p.y); pb.z = f2bf(p.z); pb.w = f2bf(p.w);
  ((ushort4*)(Pb + ((size_t)row << 10)))[tid] = pb;
}

// LDS layout for a Rx32 bf16 tile: element (r,k) at byte
//   r*64 + ((k>>3) ^ ((r>>1)&3))*16 + (k&7)*2
// -> ds_read_b128 fragment reads are 2-way (free) instead of 8-way conflicts.
__device__ __forceinline__ int lds_off(int r, int kb){
  return r * 64 + (((kb ^ ((r >> 1) & 3))) << 4);
}

__device__ __forceinline__ void gld16(void* lds, const void* g){
  __builtin_amdgcn_global_load_lds(
      (__attribute__((address_space(1))) void*)(g),
      (__attribute__((address_space(3))) void*)(lds), 16, 0, 0);
}

// ---------------------------------------------------------------------------
// Pipelined 256x128 GEMM (GEMM1 / GEMM4): C = A @ B^T, f32 accum.
// SM=0: full split, 3 MFMAs/k (22 LDS ops).  SM=2: pure bf16, 1 MFMA/k (11).
// R10 LESSON: B-in-registers from global is 2x WORSE -- per-lane fragment
// loads touch 16 cache lines/instruction (TA-path serialization).  All
// operand movement stays on the COALESCED global_load_lds path.
// 8 waves of 64x64; triple-buffered; 4 fine phases; counted vmcnt per step.
// ---------------------------------------------------------------------------
#define TILEA 16384                       // 256 rows x 64 B
#define TILEB 8192                        // 128 rows x 64 B

// EPI: 0 = write hi/lo bf16 split (o1,o2);  3 = write tanhf(x) f32 (outF)
// NT:  number of K-tiles (K = NT*32), compile-time.
// KSPLIT: A columns >= KSPLIT come from Ah2/Al2 (set KSPLIT = NT*32 to disable)
template<int EPI, int NT, int KSPLIT, int SM>
__global__ __launch_bounds__(512, 2) void gemm_pipe_kernel(
    const unsigned short* __restrict__ Ah,  const unsigned short* __restrict__ Al,
    const unsigned short* __restrict__ Ah2, const unsigned short* __restrict__ Al2,
    const unsigned short* __restrict__ Bh,  const unsigned short* __restrict__ Bl,
    int lda, int ldb,
    float* __restrict__ outF, unsigned short* __restrict__ o1,
    unsigned short* __restrict__ o2, int ldo)
{
  constexpr int OFF_AL = TILEA;                         // SM0 only
  constexpr int OFF_BH = (SM == 0) ? 2 * TILEA : TILEA;
  constexpr int OFF_BL = OFF_BH + TILEB;                // SM0/SM1 only
  constexpr int BUFSZ_T = (SM == 2) ? (OFF_BH + TILEB) : (OFF_BL + TILEB);

  __shared__ __align__(16) char sm0[BUFSZ_T];
  __shared__ __align__(16) char sm1[BUFSZ_T];
  __shared__ __align__(16) char sm2[BUFSZ_T];

  const int tid  = threadIdx.x;
  const int lane = tid & 63;
  const int w    = tid >> 6;

  int bx = blockIdx.x, by = blockIdx.y;
  { // XCD swizzle: each XCD owns a compact (gridDim.y/8)-row x 8-col chunk
    int o = bx + (by << 3);
    int xcd = o & 7, j = o >> 3;
    bx = j & 7;
    by = xcd * (gridDim.y >> 3) + (j >> 3);
  }
  const int m0 = by << 8;
  const int n0 = bx << 7;

  const unsigned short* gAh  = Ah  + (size_t)m0 * lda;
  const unsigned short* gAl  = Al  + (size_t)m0 * lda;
  const unsigned short* gAh2 = Ah2 + (size_t)m0 * lda;
  const unsigned short* gAl2 = Al2 + (size_t)m0 * lda;
  const unsigned short* gBh  = Bh  + (size_t)n0 * ldb;
  const unsigned short* gBl  = Bl  + (size_t)n0 * ldb;

  // staging: lane l covers row r0+(l>>2), PHYSICAL 16B chunk (l&3); global
  // source is LOGICAL chunk (l&3)^((r>>1)&3) (XOR involution; read side uses
  // lds_off with the same XOR -> both-sides swizzle, rule 21).
  const int rA0 = (w << 5) + (lane >> 2);
  const int rA1 = rA0 + 16;
  const int rB0 = (w << 4) + (lane >> 2);
  const int cA0 = ((lane & 3) ^ ((rA0 >> 1) & 3)) << 3;   // element offset
  const int cA1 = ((lane & 3) ^ ((rA1 >> 1) & 3)) << 3;
  const int cB0 = ((lane & 3) ^ ((rB0 >> 1) & 3)) << 3;
  const unsigned short* pAh0  = gAh  + (size_t)rA0 * lda + cA0;
  const unsigned short* pAh1  = gAh  + (size_t)rA1 * lda + cA1;
  const unsigned short* pAl0  = gAl  + (size_t)rA0 * lda + cA0;
  const unsigned short* pAl1  = gAl  + (size_t)rA1 * lda + cA1;
  const unsigned short* pAh20 = gAh2 + (size_t)rA0 * lda + cA0;
  const unsigned short* pAh21 = gAh2 + (size_t)rA1 * lda + cA1;
  const unsigned short* pAl20 = gAl2 + (size_t)rA0 * lda + cA0;
  const unsigned short* pAl21 = gAl2 + (size_t)rA1 * lda + cA1;
  const unsigned short* pBh0  = gBh  + (size_t)rB0 * ldb + cB0;
  const unsigned short* pBl0  = gBl  + (size_t)rB0 * ldb + cB0;
  const int dA0 = (w << 5) << 6;          // wave-uniform LDS byte offsets
  const int dA1 = dA0 + (16 << 6);
  const int dB0 = (w << 4) << 6;

  f32x4 acc[4][4];
  #pragma unroll
  for (int m = 0; m < 4; m++)
    #pragma unroll
    for (int n = 0; n < 4; n++)
      acc[m][n] = (f32x4){0.f, 0.f, 0.f, 0.f};

  const int wr = (w >> 1) << 6;
  const int wc = (w & 1) << 6;
  const int fr = lane & 15;
  const int kb = lane >> 4;

  short8 ah, al, bh[4], bl[4];

#define STAGE(WR, KS) do { int _k = (KS);                                   \
    const unsigned short *_s0, *_s1;                                        \
    if (KSPLIT < NT * 32 && _k >= KSPLIT){                                  \
      int _q = _k - KSPLIT;                                                 \
      _s0 = pAh20 + _q; _s1 = pAh21 + _q;                                   \
    } else { _s0 = pAh0 + _k; _s1 = pAh1 + _k; }                            \
    gld16(WR + dA0, _s0);                                                   \
    gld16(WR + dA1, _s1);                                                   \
    if constexpr (SM == 0){                                                 \
      const unsigned short *_s2, *_s3;                                      \
      if (KSPLIT < NT * 32 && _k >= KSPLIT){                                \
        int _q = _k - KSPLIT;                                               \
        _s2 = pAl20 + _q; _s3 = pAl21 + _q;                                 \
      } else { _s2 = pAl0 + _k; _s3 = pAl1 + _k; }                          \
      gld16(WR + OFF_AL + dA0, _s2);                                        \
      gld16(WR + OFF_AL + dA1, _s3);                                        \
    }                                                                       \
    gld16(WR + OFF_BH + dB0, pBh0 + _k);                                    \
    if constexpr (SM != 2)                                                  \
      gld16(WR + OFF_BL + dB0, pBl0 + _k);                                  \
  } while(0)

#define READS_B(RD) do {                                                    \
    _Pragma("unroll")                                                       \
    for (int n = 0; n < 4; n++){                                            \
      int off = lds_off(wc + n * 16 + fr, kb);                              \
      bh[n] = *(const short8*)((RD) + OFF_BH + off);                        \
      if constexpr (SM != 2)                                                \
        bl[n] = *(const short8*)((RD) + OFF_BL + off);                      \
    }                                                                       \
  } while(0)

#define READS_A(RD, M) do {                                                 \
    int off = lds_off(wr + (M) * 16 + fr, kb);                              \
    ah = *(const short8*)((RD) + off);                                      \
    if constexpr (SM == 0) al = *(const short8*)((RD) + OFF_AL + off);      \
  } while(0)

#define MFMA_M(M) do {                                                      \
    __builtin_amdgcn_s_setprio(1);                                          \
    _Pragma("unroll")                                                       \
    for (int n = 0; n < 4; n++){                                            \
      acc[M][n] = __builtin_amdgcn_mfma_f32_16x16x32_bf16(ah, bh[n], acc[M][n], 0, 0, 0); \
      if constexpr (SM != 2)                                                \
        acc[M][n] = __builtin_amdgcn_mfma_f32_16x16x32_bf16(ah, bl[n], acc[M][n], 0, 0, 0); \
      if constexpr (SM == 0)                                                \
        acc[M][n] = __builtin_amdgcn_mfma_f32_16x16x32_bf16(al, bh[n], acc[M][n], 0, 0, 0); \
    }                                                                       \
    __builtin_amdgcn_s_setprio(0);                                          \
  } while(0)

#define BAR() do { __builtin_amdgcn_s_barrier();                            \
                   asm volatile("" ::: "memory"); } while(0)
#define LGKM0() asm volatile("s_waitcnt lgkmcnt(0)" ::: "memory")
#define VMCNT_STEP() do {                                                   \
    if constexpr (SM == 0)      asm volatile("s_waitcnt vmcnt(6)" ::: "memory"); \
    else if constexpr (SM == 1) asm volatile("s_waitcnt vmcnt(4)" ::: "memory"); \
    else                        asm volatile("s_waitcnt vmcnt(3)" ::: "memory"); \
  } while(0)

// one K-step: 4 fine phases; reads issued before each barrier; one counted
// vmcnt per step boundary (retires tile T+1's loads; T+2's stay in flight).
#define STEP(RD, WR, T) do {                                                \
    int _ks = (((T) + 2 < NT) ? (T) + 2 : NT - 1) << 5;  /* dead-stage clamp */ \
    READS_B(RD); READS_A(RD, 0);                                            \
    STAGE(WR, _ks);                                                         \
    BAR(); LGKM0(); MFMA_M(0); BAR();                                       \
    READS_A(RD, 1);                                                        \
    BAR(); LGKM0(); MFMA_M(1); BAR();                                       \
    READS_A(RD, 2);                                                        \
    BAR(); LGKM0(); MFMA_M(2); BAR();                                       \
    READS_A(RD, 3);                                                        \
    BAR(); LGKM0(); MFMA_M(3);                                              \
    VMCNT_STEP();                                                           \
    BAR();                                                                  \
  } while(0)

  STAGE(sm0, 0);
  STAGE(sm1, 32);
  VMCNT_STEP();   // tile 0 landed
  BAR();

  for (int t = 0; t < NT; t += 3){
    STEP(sm0, sm2, t);
    if (t + 1 < NT) STEP(sm1, sm0, t + 1);
    if (t + 2 < NT) STEP(sm2, sm1, t + 2);
  }
#undef STAGE
#undef READS_B
#undef READS_A
#undef MFMA_M
#undef BAR
#undef LGKM0
#undef VMCNT_STEP
#undef STEP

  // epilogue: C/D layout col = lane&15, row = (lane>>4)*4 + reg  [m89-verified]
  const int rbase = (lane >> 4) << 2;
  const int cbase = lane & 15;
  #pragma unroll
  for (int m = 0; m < 4; m++){
    #pragma unroll
    for (int n = 0; n < 4; n++){
      f32x4 v = acc[m][n];
      int col = n0 + wc + n * 16 + cbase;
      #pragma unroll
      for (int j = 0; j < 4; j++){
        int row = m0 + wr + m * 16 + rbase + j;
        float val = v[j];
        size_t idx = (size_t)row * ldo + col;
        if (EPI == 0){
          unsigned short h = f2bf(val);
          o1[idx] = h;
          o2[idx] = f2bf(val - bf2f(h));
        } else {
          outF[idx] = tanhf(val);
        }
      }
    }
  }
}

// ---------------------------------------------------------------------------
// 128^2 kernel for the batched GEMMs (len-skip / len-clamp).  Staging now
// uses COALESCED global_load_lds with pre-swizzled global source (same
// both-sides-swizzle as the pipe kernel; read side unchanged -> results
// bit-identical).  Removes 8 (SPLIT) / 4 ds_writes + VGPR roundtrips per
// K-step.  __syncthreads after STAGE drains vmcnt (m97 structure).
// EPI: 0 = split bf16 out; 1 = f32 out; 3 = tanh f32 out; 4 = bf16 out.
// ---------------------------------------------------------------------------
template<bool SPLIT, int EPI>
__global__ __launch_bounds__(256, 2) void gemm_kernel(
    const unsigned short* __restrict__ Ah, const unsigned short* __restrict__ Al,
    const unsigned short* __restrict__ Bh, const unsigned short* __restrict__ Bl,
    int K, int lda, int ldb,
    long long aStride, long long bStride, long long oStride,
    float* __restrict__ outF, unsigned short* __restrict__ o1,
    unsigned short* __restrict__ o2, int ldo,
    const int* __restrict__ lens, int lmode)
{
  constexpr int TILE = 128 * 64;  // bytes per staged tile
  __shared__ __align__(16) char smem[(SPLIT ? 4 : 2) * TILE];
  char* sAh = smem;
  char* sBh = smem + TILE;
  char* sAl = smem + (SPLIT ? 2 : 0) * TILE;
  char* sBl = smem + (SPLIT ? 3 : 0) * TILE;

  const int tid  = threadIdx.x;
  const int lane = tid & 63;
  const int wid  = tid >> 6;
  const int z    = blockIdx.z;

  int bx = blockIdx.x, by = blockIdx.y;
  if (gridDim.x == 8 && gridDim.y == 8){
    int o = bx + (by << 3);
    int k = o & 7, j = o >> 3;
    bx = ((k & 3) << 1) | (j & 1);  by = ((k >> 2) << 2) | (j >> 1);
  }
  const int m0 = by * 128;
  const int n0 = bx * 128;

  int Keff = K;
  if (lmode){
    const int len = lens[z];
    if (lmode == 1 && n0 >= len) return;       // output fully masked downstream
    if (lmode == 2){
      int kc = (len + 31) & ~31;
      Keff = kc < K ? kc : K;                  // P is exactly 0 beyond len
    }
  }

  const unsigned short* gAh = Ah + (size_t)z * aStride + (size_t)m0 * lda;
  const unsigned short* gBh = Bh + (size_t)z * bStride + (size_t)n0 * ldb;
  const unsigned short* gAl = SPLIT ? (Al + (size_t)z * aStride + (size_t)m0 * lda) : (const unsigned short*)0;
  const unsigned short* gBl = SPLIT ? (Bl + (size_t)z * bStride + (size_t)n0 * ldb) : (const unsigned short*)0;

  // gld16 staging plan: wave w covers rows 32w..32w+31 of the 128-row A and
  // B tiles (2 gld16 per tile half).  lane l -> row rS+(l>>2), physical
  // chunk (l&3); global source chunk (l&3)^((r>>1)&3)  (pre-swizzled source,
  // linear LDS dest -- rule 21; read side lds_off unchanged).
  const int rS0 = (wid << 5) + (lane >> 2);
  const int rS1 = rS0 + 16;
  const int cS0 = ((lane & 3) ^ ((rS0 >> 1) & 3)) << 3;
  const int cS1 = ((lane & 3) ^ ((rS1 >> 1) & 3)) << 3;
  const int dS0 = (wid << 5) << 6;
  const int dS1 = dS0 + (16 << 6);
  const unsigned short* qAh0 = gAh + (size_t)rS0 * lda + cS0;
  const unsigned short* qAh1 = gAh + (size_t)rS1 * lda + cS1;
  const unsigned short* qBh0 = gBh + (size_t)rS0 * ldb + cS0;
  const unsigned short* qBh1 = gBh + (size_t)rS1 * ldb + cS1;
  const unsigned short* qAl0 = SPLIT ? (gAl + (size_t)rS0 * lda + cS0) : (const unsigned short*)0;
  const unsigned short* qAl1 = SPLIT ? (gAl + (size_t)rS1 * lda + cS1) : (const unsigned short*)0;
  const unsigned short* qBl0 = SPLIT ? (gBl + (size_t)rS0 * ldb + cS0) : (const unsigned short*)0;
  const unsigned short* qBl1 = SPLIT ? (gBl + (size_t)rS1 * ldb + cS1) : (const unsigned short*)0;

  f32x4 acc[4][4];
  #pragma unroll
  for (int m = 0; m < 4; m++)
    #pragma unroll
    for (int n = 0; n < 4; n++)
      acc[m][n] = (f32x4){0.f, 0.f, 0.f, 0.f};

  const int wr = (wid >> 1) * 64;
  const int wc = (wid & 1) * 64;
  const int fr = lane & 15;
  const int kb = lane >> 4;

  for (int k0 = 0; k0 < Keff; k0 += 32){
    __syncthreads();                      // WAR: all reads of prev tile done
    gld16(sAh + dS0, qAh0 + k0);
    gld16(sAh + dS1, qAh1 + k0);
    gld16(sBh + dS0, qBh0 + k0);
    gld16(sBh + dS1, qBh1 + k0);
    if (SPLIT){
      gld16(sAl + dS0, qAl0 + k0);
      gld16(sAl + dS1, qAl1 + k0);
      gld16(sBl + dS0, qBl0 + k0);
      gld16(sBl + dS1, qBl1 + k0);
    }
    __syncthreads();                      // drains vmcnt -> tile visible

    short8 ah[4], bh[4], al[4], bl[4];
    #pragma unroll
    for (int m = 0; m < 4; m++){
      int off = lds_off(wr + m * 16 + fr, kb);
      ah[m] = *(const short8*)(sAh + off);
      if (SPLIT) al[m] = *(const short8*)(sAl + off);
    }
    #pragma unroll
    for (int n = 0; n < 4; n++){
      int off = lds_off(wc + n * 16 + fr, kb);
      bh[n] = *(const short8*)(sBh + off);
      if (SPLIT) bl[n] = *(const short8*)(sBl + off);
    }
    #pragma unroll
    for (int m = 0; m < 4; m++)
      #pragma unroll
      for (int n = 0; n < 4; n++){
        acc[m][n] = __builtin_amdgcn_mfma_f32_16x16x32_bf16(ah[m], bh[n], acc[m][n], 0, 0, 0);
        if (SPLIT){
          acc[m][n] = __builtin_amdgcn_mfma_f32_16x16x32_bf16(ah[m], bl[n], acc[m][n], 0, 0, 0);
          acc[m][n] = __builtin_amdgcn_mfma_f32_16x16x32_bf16(al[m], bh[n], acc[m][n], 0, 0, 0);
        }
      }
  }

  const int rbase = (lane >> 4) * 2 * 2;
  const int cbase = lane & 15;
  #pragma unroll
  for (int m = 0; m < 4; m++){
    #pragma unroll
    for (int n = 0; n < 4; n++){
      f32x4 v = acc[m][n];
      int col = n0 + wc + n * 16 + cbase;
      #pragma unroll
      for (int j = 0; j < 4; j++){
        int row = m0 + wr + m * 16 + rbase + j;
        float val = v[j];
        size_t idx = (size_t)row * ldo + col;
        if (EPI == 0){
          unsigned short h = f2bf(val);
          o1[(size_t)z * oStride + idx] = h;
          o2[(size_t)z * oStride + idx] = f2bf(val - bf2f(h));
        } else if (EPI == 1){
          outF[(size_t)z * oStride + idx] = val;
        } else if (EPI == 4){
          o1[(size_t)z * oStride + idx] = f2bf(val);
        } else {
          outF[idx] = tanhf(val);
        }
      }
    }
  }
}

extern "C" void kernel_launch(void* const* d_in, const int* in_sizes, int n_in,
                              void* d_out, int out_size, void* d_ws, size_t ws_size,
                              hipStream_t stream){
  const float* input   = (const float*)d_in[0];
  const float* context = (const float*)d_in[1];
  const int*   lens    = (const int*)d_in[2];
  const float* Win     = (const float*)d_in[3];
  const float* Wout    = (const float*)d_in[4];
  float* attn  = (float*)d_out;
  float* align = attn + (size_t)BT * DIM;

  char* ws = (char*)d_ws;
  size_t off = 0;
  auto alloc = [&](size_t bytes) -> char* {
    char* p = ws + off; off += (bytes + 255) & ~(size_t)255; return p;
  };
  const size_t MTD = (size_t)BT * DIM;   // 8M elements
  unsigned short* in_hi = (unsigned short*)alloc(MTD * 2);
  unsigned short* in_lo = (unsigned short*)alloc(MTD * 2);
  unsigned short* cx_hi = (unsigned short*)alloc(MTD * 2);
  unsigned short* cx_lo = (unsigned short*)alloc(MTD * 2);
  unsigned short* wi_hi = (unsigned short*)alloc((size_t)DIM * DIM * 2);
  unsigned short* wi_lo = (unsigned short*)alloc((size_t)DIM * DIM * 2);
  unsigned short* ht_hi = (unsigned short*)alloc(MTD * 2);
  unsigned short* ht_lo = (unsigned short*)alloc(MTD * 2);
  unsigned short* cxT   = (unsigned short*)alloc(MTD * 2);
  unsigned short* c_hi  = (unsigned short*)alloc(MTD * 2);   // GEMM3 out (plain bf16)
  unsigned short* wo_hi = (unsigned short*)alloc((size_t)DIM * 2 * DIM * 2);
  unsigned short* p_bf  = cx_hi;   // alias: cx_hi dead after GEMM2
  if (off > ws_size) return;

  // prep: splits + W conversions + fused context split/transpose
  split_kernel<<<4096, 256, 0, stream>>>(input, in_hi, in_lo, (int)(MTD >> 2));
  split_kernel<<<1024, 256, 0, stream>>>(Win, wi_hi, wi_lo, (DIM * DIM) >> 2);
  cvt_kernel<<<2048, 256, 0, stream>>>(Wout, wo_hi, (DIM * 2 * DIM) >> 2);
  ctx_prep_kernel<<<dim3(16, 16, NBAT), dim3(64, 4), 0, stream>>>(context, cx_hi, cx_lo, cxT);

  // GEMM1: ht = input @ Win^T   (pipelined SM0 full split -- score path)
  gemm_pipe_kernel<0, 32, 1024, 0><<<dim3(8, 32), 512, 0, stream>>>(
      in_hi, in_lo, in_hi, in_lo, wi_hi, wi_lo, DIM, DIM,
      nullptr, ht_hi, ht_lo, DIM);
  // GEMM2: scores[b] = ht[b] @ ctx[b]^T  (split in, f32 out -> align region)
  gemm_kernel<true, 1><<<dim3(8, 8, NBAT), 256, 0, stream>>>(
      ht_hi, ht_lo, cx_hi, cx_lo, DIM, DIM, DIM,
      (long long)DIM * 1024, (long long)DIM * 1024, (long long)DIM * 1024,
      align, nullptr, nullptr, DIM, lens, 1);
  // masked softmax (in-place on align) + P bf16
  softmax_kernel<<<BT, 256, 0, stream>>>(align, p_bf, lens);
  // GEMM3: c[b] = P[b] @ ctxT[b]^T  (plain bf16 in, single bf16 out)
  gemm_kernel<false, 4><<<dim3(8, 8, NBAT), 256, 0, stream>>>(
      p_bf, nullptr, cxT, nullptr, DIM, DIM, DIM,
      (long long)DIM * 1024, (long long)DIM * 1024, (long long)1024 * 1024,
      nullptr, c_hi, nullptr, DIM, lens, 2);
  // GEMM4: attn = tanh([c | input] @ Wout^T)  (pipelined SM2 pure bf16)
  gemm_pipe_kernel<3, 64, 1024, 2><<<dim3(8, 32), 512, 0, stream>>>(
      c_hi, c_hi, in_hi, in_hi, wo_hi, wo_hi, DIM, 2 * DIM,
      attn, nullptr, nullptr, DIM);
}

// Round 12
// 222.829 us; speedup vs baseline: 1.4893x; 1.0252x over previous
//
#include <hip/hip_runtime.h>

typedef __attribute__((ext_vector_type(8))) short short8;
typedef __attribute__((ext_vector_type(4))) float f32x4;

#define DIM  1024
#define BT   8192   // B * TGT rows
#define NBAT 8

__device__ __forceinline__ unsigned short f2bf(float x){
  union { float f; unsigned u; } un; un.f = x;
  unsigned r = un.u + 0x7fffu + ((un.u >> 16) & 1u);   // round-to-nearest-even
  return (unsigned short)(r >> 16);
}
__device__ __forceinline__ float bf2f(unsigned short h){
  union { unsigned u; float f; } un; un.u = ((unsigned)h) << 16;
  return un.f;
}

// split f32 -> hi/lo bf16
__global__ void split_kernel(const float* __restrict__ x,
                             unsigned short* __restrict__ hi,
                             unsigned short* __restrict__ lo,
                             int n4){
  int stride = gridDim.x * blockDim.x;
  for (int i = blockIdx.x * blockDim.x + threadIdx.x; i < n4; i += stride){
    float4 v = ((const float4*)x)[i];
    ushort4 h, l;
    h.x = f2bf(v.x); l.x = f2bf(v.x - bf2f(h.x));
    h.y = f2bf(v.y); l.y = f2bf(v.y - bf2f(h.y));
    h.z = f2bf(v.z); l.z = f2bf(v.z - bf2f(h.z));
    h.w = f2bf(v.w); l.w = f2bf(v.w - bf2f(h.w));
    ((ushort4*)hi)[i] = h;
    ((ushort4*)lo)[i] = l;
  }
}

// plain f32 -> bf16 convert (Wout: lo term not used by GEMM4 SM2)
__global__ void cvt_kernel(const float* __restrict__ x,
                           unsigned short* __restrict__ hi, int n4){
  int stride = gridDim.x * blockDim.x;
  for (int i = blockIdx.x * blockDim.x + threadIdx.x; i < n4; i += stride){
    float4 v = ((const float4*)x)[i];
    ushort4 h;
    h.x = f2bf(v.x); h.y = f2bf(v.y); h.z = f2bf(v.z); h.w = f2bf(v.w);
    ((ushort4*)hi)[i] = h;
  }
}

// fused: context [b][s][d] f32 -> cx_hi/cx_lo [b][s][d] bf16 + ctxT [b][d][s]
// bf16 (hi).  Single read of context.
__global__ void ctx_prep_kernel(const float* __restrict__ ctx,
                                unsigned short* __restrict__ hi,
                                unsigned short* __restrict__ lo,
                                unsigned short* __restrict__ ctxT){
  __shared__ unsigned short t[64][65];
  int bz = blockIdx.z;
  int s0 = blockIdx.x << 6, d0 = blockIdx.y << 6;
  int tx = threadIdx.x, ty = threadIdx.y;   // (64,4)
  const size_t base = (((size_t)bz << 10) + s0) * DIM + d0;
  const float* src = ctx + base;
  unsigned short* hrow = hi + base;
  unsigned short* lrow = lo + base;
  #pragma unroll
  for (int i = ty; i < 64; i += 4){
    float v = src[(size_t)i * DIM + tx];
    unsigned short h = f2bf(v);
    hrow[(size_t)i * DIM + tx] = h;
    lrow[(size_t)i * DIM + tx] = f2bf(v - bf2f(h));
    t[i][tx] = h;
  }
  __syncthreads();
  unsigned short* dst = ctxT + (((size_t)bz << 10) + d0) * DIM + s0;
  #pragma unroll
  for (int i = ty; i < 64; i += 4)
    dst[(size_t)i * DIM + tx] = t[tx][i];
}

// masked softmax over rows of 1024; P f32 in place + P bf16 to Pb.
// Fully-masked words not loaded; output bit-identical.
__global__ __launch_bounds__(256) void softmax_kernel(float* __restrict__ sc,
                                                      unsigned short* __restrict__ Pb,
                                                      const int* __restrict__ lens){
  const int row = blockIdx.x;
  const int len = lens[row >> 10];
  const int tid = threadIdx.x;
  const int lane = tid & 63, wid = tid >> 6;
  float* rp = sc + ((size_t)row << 10);
  const int s0 = tid << 2;
  float4 v;
  if (s0 < len) v = ((const float4*)rp)[tid];
  else          v = (float4){0.f, 0.f, 0.f, 0.f};
  float x0 = (s0 + 0 < len) ? v.x : -INFINITY;
  float x1 = (s0 + 1 < len) ? v.y : -INFINITY;
  float x2 = (s0 + 2 < len) ? v.z : -INFINITY;
  float x3 = (s0 + 3 < len) ? v.w : -INFINITY;
  float wmax = fmaxf(fmaxf(x0, x1), fmaxf(x2, x3));
  #pragma unroll
  for (int o = 32; o > 0; o >>= 1) wmax = fmaxf(wmax, __shfl_xor(wmax, o));
  __shared__ float red[8];
  if (lane == 0) red[wid] = wmax;
  __syncthreads();
  float mx = fmaxf(fmaxf(red[0], red[1]), fmaxf(red[2], red[3]));
  float e0 = (s0 + 0 < len) ? __expf(x0 - mx) : 0.f;
  float e1 = (s0 + 1 < len) ? __expf(x1 - mx) : 0.f;
  float e2 = (s0 + 2 < len) ? __expf(x2 - mx) : 0.f;
  float e3 = (s0 + 3 < len) ? __expf(x3 - mx) : 0.f;
  float ws = e0 + e1 + e2 + e3;
  #pragma unroll
  for (int o = 32; o > 0; o >>= 1) ws += __shfl_xor(ws, o);
  if (lane == 0) red[4 + wid] = ws;
  __syncthreads();
  float inv = 1.f / (red[4] + red[5] + red[6] + red[7]);
  float4 p; p.x = e0 * inv; p.y = e1 * inv; p.z = e2 * inv; p.w = e3 * inv;
  ((float4*)rp)[tid] = p;
  ushort4 pb; pb.x = f2bf(p.x); pb.y = f2bf(p.y); pb.z = f2bf(p.z); pb.w = f2bf(p.w);
  ((ushort4*)(Pb + ((size_t)row << 10)))[tid] = pb;
}

// LDS layout for a Rx32 bf16 tile: element (r,k) at byte
//   r*64 + ((k>>3) ^ ((r>>1)&3))*16 + (k&7)*2
// -> ds_read_b128 fragment reads are 2-way (free) instead of 8-way conflicts.
__device__ __forceinline__ int lds_off(int r, int kb){
  return r * 64 + (((kb ^ ((r >> 1) & 3))) << 4);
}

__device__ __forceinline__ void gld16(void* lds, const void* g){
  __builtin_amdgcn_global_load_lds(
      (__attribute__((address_space(1))) void*)(g),
      (__attribute__((address_space(3))) void*)(lds), 16, 0, 0);
}

// ---------------------------------------------------------------------------
// Pipelined 256x128 GEMM (GEMM1): C = A @ B^T, f32 accum.
// SM=0: full split, 3 MFMAs/k (22 LDS ops).  SM=2: pure bf16, 1 MFMA/k (11).
// R10 LESSON: B-in-registers from global is 2x WORSE (per-lane fragment loads
// touch 16 cache lines/instr).  All movement stays on coalesced gld16 path.
// 8 waves of 64x64; triple-buffered; 4 fine phases; counted vmcnt per step.
// ---------------------------------------------------------------------------
#define TILEA 16384                       // 256 rows x 64 B
#define TILEB 8192                        // 128 rows x 64 B

// EPI: 0 = write hi/lo bf16 split (o1,o2);  3 = write tanhf(x) f32 (outF)
// NT:  number of K-tiles (K = NT*32), compile-time.
// KSPLIT: A columns >= KSPLIT come from Ah2/Al2 (set KSPLIT = NT*32 to disable)
template<int EPI, int NT, int KSPLIT, int SM>
__global__ __launch_bounds__(512, 2) void gemm_pipe_kernel(
    const unsigned short* __restrict__ Ah,  const unsigned short* __restrict__ Al,
    const unsigned short* __restrict__ Ah2, const unsigned short* __restrict__ Al2,
    const unsigned short* __restrict__ Bh,  const unsigned short* __restrict__ Bl,
    int lda, int ldb,
    float* __restrict__ outF, unsigned short* __restrict__ o1,
    unsigned short* __restrict__ o2, int ldo)
{
  constexpr int OFF_AL = TILEA;                         // SM0 only
  constexpr int OFF_BH = (SM == 0) ? 2 * TILEA : TILEA;
  constexpr int OFF_BL = OFF_BH + TILEB;                // SM0/SM1 only
  constexpr int BUFSZ_T = (SM == 2) ? (OFF_BH + TILEB) : (OFF_BL + TILEB);

  __shared__ __align__(16) char sm0[BUFSZ_T];
  __shared__ __align__(16) char sm1[BUFSZ_T];
  __shared__ __align__(16) char sm2[BUFSZ_T];

  const int tid  = threadIdx.x;
  const int lane = tid & 63;
  const int w    = tid >> 6;

  int bx = blockIdx.x, by = blockIdx.y;
  { // XCD swizzle: each XCD owns a compact (gridDim.y/8)-row x 8-col chunk
    int o = bx + (by << 3);
    int xcd = o & 7, j = o >> 3;
    bx = j & 7;
    by = xcd * (gridDim.y >> 3) + (j >> 3);
  }
  const int m0 = by << 8;
  const int n0 = bx << 7;

  const unsigned short* gAh  = Ah  + (size_t)m0 * lda;
  const unsigned short* gAl  = Al  + (size_t)m0 * lda;
  const unsigned short* gAh2 = Ah2 + (size_t)m0 * lda;
  const unsigned short* gAl2 = Al2 + (size_t)m0 * lda;
  const unsigned short* gBh  = Bh  + (size_t)n0 * ldb;
  const unsigned short* gBl  = Bl  + (size_t)n0 * ldb;

  // staging: lane l covers row r0+(l>>2), PHYSICAL 16B chunk (l&3); global
  // source is LOGICAL chunk (l&3)^((r>>1)&3) (XOR involution; read side uses
  // lds_off with the same XOR -> both-sides swizzle, rule 21).
  const int rA0 = (w << 5) + (lane >> 2);
  const int rA1 = rA0 + 16;
  const int rB0 = (w << 4) + (lane >> 2);
  const int cA0 = ((lane & 3) ^ ((rA0 >> 1) & 3)) << 3;   // element offset
  const int cA1 = ((lane & 3) ^ ((rA1 >> 1) & 3)) << 3;
  const int cB0 = ((lane & 3) ^ ((rB0 >> 1) & 3)) << 3;
  const unsigned short* pAh0  = gAh  + (size_t)rA0 * lda + cA0;
  const unsigned short* pAh1  = gAh  + (size_t)rA1 * lda + cA1;
  const unsigned short* pAl0  = gAl  + (size_t)rA0 * lda + cA0;
  const unsigned short* pAl1  = gAl  + (size_t)rA1 * lda + cA1;
  const unsigned short* pAh20 = gAh2 + (size_t)rA0 * lda + cA0;
  const unsigned short* pAh21 = gAh2 + (size_t)rA1 * lda + cA1;
  const unsigned short* pAl20 = gAl2 + (size_t)rA0 * lda + cA0;
  const unsigned short* pAl21 = gAl2 + (size_t)rA1 * lda + cA1;
  const unsigned short* pBh0  = gBh  + (size_t)rB0 * ldb + cB0;
  const unsigned short* pBl0  = gBl  + (size_t)rB0 * ldb + cB0;
  const int dA0 = (w << 5) << 6;          // wave-uniform LDS byte offsets
  const int dA1 = dA0 + (16 << 6);
  const int dB0 = (w << 4) << 6;

  f32x4 acc[4][4];
  #pragma unroll
  for (int m = 0; m < 4; m++)
    #pragma unroll
    for (int n = 0; n < 4; n++)
      acc[m][n] = (f32x4){0.f, 0.f, 0.f, 0.f};

  const int wr = (w >> 1) << 6;
  const int wc = (w & 1) << 6;
  const int fr = lane & 15;
  const int kb = lane >> 4;

  short8 ah, al, bh[4], bl[4];

#define STAGE(WR, KS) do { int _k = (KS);                                   \
    const unsigned short *_s0, *_s1;                                        \
    if (KSPLIT < NT * 32 && _k >= KSPLIT){                                  \
      int _q = _k - KSPLIT;                                                 \
      _s0 = pAh20 + _q; _s1 = pAh21 + _q;                                   \
    } else { _s0 = pAh0 + _k; _s1 = pAh1 + _k; }                            \
    gld16(WR + dA0, _s0);                                                   \
    gld16(WR + dA1, _s1);                                                   \
    if constexpr (SM == 0){                                                 \
      const unsigned short *_s2, *_s3;                                      \
      if (KSPLIT < NT * 32 && _k >= KSPLIT){                                \
        int _q = _k - KSPLIT;                                               \
        _s2 = pAl20 + _q; _s3 = pAl21 + _q;                                 \
      } else { _s2 = pAl0 + _k; _s3 = pAl1 + _k; }                          \
      gld16(WR + OFF_AL + dA0, _s2);                                        \
      gld16(WR + OFF_AL + dA1, _s3);                                        \
    }                                                                       \
    gld16(WR + OFF_BH + dB0, pBh0 + _k);                                    \
    if constexpr (SM != 2)                                                  \
      gld16(WR + OFF_BL + dB0, pBl0 + _k);                                  \
  } while(0)

#define READS_B(RD) do {                                                    \
    _Pragma("unroll")                                                       \
    for (int n = 0; n < 4; n++){                                            \
      int off = lds_off(wc + n * 16 + fr, kb);                              \
      bh[n] = *(const short8*)((RD) + OFF_BH + off);                        \
      if constexpr (SM != 2)                                                \
        bl[n] = *(const short8*)((RD) + OFF_BL + off);                      \
    }                                                                       \
  } while(0)

#define READS_A(RD, M) do {                                                 \
    int off = lds_off(wr + (M) * 16 + fr, kb);                              \
    ah = *(const short8*)((RD) + off);                                      \
    if constexpr (SM == 0) al = *(const short8*)((RD) + OFF_AL + off);      \
  } while(0)

#define MFMA_M(M) do {                                                      \
    __builtin_amdgcn_s_setprio(1);                                          \
    _Pragma("unroll")                                                       \
    for (int n = 0; n < 4; n++){                                            \
      acc[M][n] = __builtin_amdgcn_mfma_f32_16x16x32_bf16(ah, bh[n], acc[M][n], 0, 0, 0); \
      if constexpr (SM != 2)                                                \
        acc[M][n] = __builtin_amdgcn_mfma_f32_16x16x32_bf16(ah, bl[n], acc[M][n], 0, 0, 0); \
      if constexpr (SM == 0)                                                \
        acc[M][n] = __builtin_amdgcn_mfma_f32_16x16x32_bf16(al, bh[n], acc[M][n], 0, 0, 0); \
    }                                                                       \
    __builtin_amdgcn_s_setprio(0);                                          \
  } while(0)

#define BAR() do { __builtin_amdgcn_s_barrier();                            \
                   asm volatile("" ::: "memory"); } while(0)
#define LGKM0() asm volatile("s_waitcnt lgkmcnt(0)" ::: "memory")
#define VMCNT_STEP() do {                                                   \
    if constexpr (SM == 0)      asm volatile("s_waitcnt vmcnt(6)" ::: "memory"); \
    else if constexpr (SM == 1) asm volatile("s_waitcnt vmcnt(4)" ::: "memory"); \
    else                        asm volatile("s_waitcnt vmcnt(3)" ::: "memory"); \
  } while(0)

#define STEP(RD, WR, T) do {                                                \
    int _ks = (((T) + 2 < NT) ? (T) + 2 : NT - 1) << 5;  /* dead-stage clamp */ \
    READS_B(RD); READS_A(RD, 0);                                            \
    STAGE(WR, _ks);                                                         \
    BAR(); LGKM0(); MFMA_M(0); BAR();                                       \
    READS_A(RD, 1);                                                        \
    BAR(); LGKM0(); MFMA_M(1); BAR();                                       \
    READS_A(RD, 2);                                                        \
    BAR(); LGKM0(); MFMA_M(2); BAR();                                       \
    READS_A(RD, 3);                                                        \
    BAR(); LGKM0(); MFMA_M(3);                                              \
    VMCNT_STEP();                                                           \
    BAR();                                                                  \
  } while(0)

  STAGE(sm0, 0);
  STAGE(sm1, 32);
  VMCNT_STEP();   // tile 0 landed
  BAR();

  for (int t = 0; t < NT; t += 3){
    STEP(sm0, sm2, t);
    if (t + 1 < NT) STEP(sm1, sm0, t + 1);
    if (t + 2 < NT) STEP(sm2, sm1, t + 2);
  }
#undef STAGE
#undef READS_B
#undef READS_A
#undef MFMA_M
#undef BAR
#undef LGKM0
#undef VMCNT_STEP
#undef STEP

  // epilogue: C/D layout col = lane&15, row = (lane>>4)*4 + reg  [m89-verified]
  const int rbase = (lane >> 4) << 2;
  const int cbase = lane & 15;
  #pragma unroll
  for (int m = 0; m < 4; m++){
    #pragma unroll
    for (int n = 0; n < 4; n++){
      f32x4 v = acc[m][n];
      int col = n0 + wc + n * 16 + cbase;
      #pragma unroll
      for (int j = 0; j < 4; j++){
        int row = m0 + wr + m * 16 + rbase + j;
        float val = v[j];
        size_t idx = (size_t)row * ldo + col;
        if (EPI == 0){
          unsigned short h = f2bf(val);
          o1[idx] = h;
          o2[idx] = f2bf(val - bf2f(h));
        } else {
          outF[idx] = tanhf(val);
        }
      }
    }
  }
}

// ---------------------------------------------------------------------------
// GEMM4 kernel: 128x128-tile pipe, 4 waves of 64x64 (proven per-wave shape),
// pure bf16 (1 MFMA/k), A split at KSPLIT ([c | input]).  48KB LDS total ->
// 3 blocks/CU co-resident (vs 1 for the 256x128 pipe): cross-block overlap
// hides the barrier/drain overhead that left SM2 at ~60% of its LDS-op floor.
// Same counted-vmcnt ledger: 4 loads/step, vmcnt(4) retires tile T+1.
// ---------------------------------------------------------------------------
template<int EPI, int NT, int KSPLIT>
__global__ __launch_bounds__(256, 2) void gemm_pipe128_kernel(
    const unsigned short* __restrict__ Ah, const unsigned short* __restrict__ Ah2,
    const unsigned short* __restrict__ Bh,
    int lda, int ldb,
    float* __restrict__ outF, unsigned short* __restrict__ o1, int ldo)
{
  constexpr int TA  = 8192;               // 128 rows x 64 B
  constexpr int OFF_B = TA;
  constexpr int BUF = 2 * TA;             // 16 KB

  __shared__ __align__(16) char sm0[BUF];
  __shared__ __align__(16) char sm1[BUF];
  __shared__ __align__(16) char sm2[BUF];

  const int tid  = threadIdx.x;
  const int lane = tid & 63;
  const int w    = tid >> 6;              // 0..3

  int bx = blockIdx.x, by = blockIdx.y;
  { // XCD swizzle (grid (8,64))
    int o = bx + (by << 3);
    int xcd = o & 7, j = o >> 3;
    bx = j & 7;
    by = xcd * (gridDim.y >> 3) + (j >> 3);
  }
  const int m0 = by << 7;
  const int n0 = bx << 7;

  const unsigned short* gAh  = Ah  + (size_t)m0 * lda;
  const unsigned short* gAh2 = Ah2 + (size_t)m0 * lda;
  const unsigned short* gBh  = Bh  + (size_t)n0 * ldb;

  // staging: wave w covers rows 32w..32w+31 of the 128-row A and B tiles
  // (2 gld16 each).  Pre-swizzled global source, linear LDS dest (rule 21).
  const int rS0 = (w << 5) + (lane >> 2);
  const int rS1 = rS0 + 16;
  const int cS0 = ((lane & 3) ^ ((rS0 >> 1) & 3)) << 3;
  const int cS1 = ((lane & 3) ^ ((rS1 >> 1) & 3)) << 3;
  const unsigned short* pA0  = gAh  + (size_t)rS0 * lda + cS0;
  const unsigned short* pA1  = gAh  + (size_t)rS1 * lda + cS1;
  const unsigned short* pA20 = gAh2 + (size_t)rS0 * lda + cS0;
  const unsigned short* pA21 = gAh2 + (size_t)rS1 * lda + cS1;
  const unsigned short* pB0  = gBh  + (size_t)rS0 * ldb + cS0;
  const unsigned short* pB1  = gBh  + (size_t)rS1 * ldb + cS1;
  const int dS0 = (w << 5) << 6;
  const int dS1 = dS0 + (16 << 6);

  f32x4 acc[4][4];
  #pragma unroll
  for (int m = 0; m < 4; m++)
    #pragma unroll
    for (int n = 0; n < 4; n++)
      acc[m][n] = (f32x4){0.f, 0.f, 0.f, 0.f};

  const int wr = (w >> 1) << 6;
  const int wc = (w & 1) << 6;
  const int fr = lane & 15;
  const int kb = lane >> 4;

  short8 ah, bh[4];

#define STAGE(WR, KS) do { int _k = (KS);                                   \
    const unsigned short *_s0, *_s1;                                        \
    if (_k >= KSPLIT){ int _q = _k - KSPLIT; _s0 = pA20 + _q; _s1 = pA21 + _q; } \
    else             { _s0 = pA0 + _k;       _s1 = pA1 + _k; }              \
    gld16(WR + dS0, _s0);                                                   \
    gld16(WR + dS1, _s1);                                                   \
    gld16(WR + OFF_B + dS0, pB0 + _k);                                      \
    gld16(WR + OFF_B + dS1, pB1 + _k);                                      \
  } while(0)

#define READS_B(RD) do {                                                    \
    _Pragma("unroll")                                                       \
    for (int n = 0; n < 4; n++)                                             \
      bh[n] = *(const short8*)((RD) + OFF_B + lds_off(wc + n * 16 + fr, kb)); \
  } while(0)

#define READS_A(RD, M)                                                      \
    ah = *(const short8*)((RD) + lds_off(wr + (M) * 16 + fr, kb))

#define MFMA_M(M) do {                                                      \
    __builtin_amdgcn_s_setprio(1);                                          \
    _Pragma("unroll")                                                       \
    for (int n = 0; n < 4; n++)                                             \
      acc[M][n] = __builtin_amdgcn_mfma_f32_16x16x32_bf16(ah, bh[n], acc[M][n], 0, 0, 0); \
    __builtin_amdgcn_s_setprio(0);                                          \
  } while(0)

#define BAR() do { __builtin_amdgcn_s_barrier();                            \
                   asm volatile("" ::: "memory"); } while(0)
#define LGKM0() asm volatile("s_waitcnt lgkmcnt(0)" ::: "memory")
#define VMCNT4() asm volatile("s_waitcnt vmcnt(4)" ::: "memory")

#define STEP(RD, WR, T) do {                                                \
    int _ks = (((T) + 2 < NT) ? (T) + 2 : NT - 1) << 5;  /* dead-stage clamp */ \
    READS_B(RD); READS_A(RD, 0);                                            \
    STAGE(WR, _ks);                                                         \
    BAR(); LGKM0(); MFMA_M(0); BAR();                                       \
    READS_A(RD, 1);                                                        \
    BAR(); LGKM0(); MFMA_M(1); BAR();                                       \
    READS_A(RD, 2);                                                        \
    BAR(); LGKM0(); MFMA_M(2); BAR();                                       \
    READS_A(RD, 3);                                                        \
    BAR(); LGKM0(); MFMA_M(3);                                              \
    VMCNT4();                                                               \
    BAR();                                                                  \
  } while(0)

  STAGE(sm0, 0);
  STAGE(sm1, 32);
  VMCNT4();       // retires tile 0's 4 loads
  BAR();

  for (int t = 0; t < NT; t += 3){
    STEP(sm0, sm2, t);
    if (t + 1 < NT) STEP(sm1, sm0, t + 1);
    if (t + 2 < NT) STEP(sm2, sm1, t + 2);
  }
#undef STAGE
#undef READS_B
#undef READS_A
#undef MFMA_M
#undef BAR
#undef LGKM0
#undef VMCNT4
#undef STEP

  // epilogue: C/D layout col = lane&15, row = (lane>>4)*4 + reg  [m89-verified]
  const int rbase = (lane >> 4) << 2;
  const int cbase = lane & 15;
  #pragma unroll
  for (int m = 0; m < 4; m++){
    #pragma unroll
    for (int n = 0; n < 4; n++){
      f32x4 v = acc[m][n];
      int col = n0 + wc + n * 16 + cbase;
      #pragma unroll
      for (int j = 0; j < 4; j++){
        int row = m0 + wr + m * 16 + rbase + j;
        float val = v[j];
        size_t idx = (size_t)row * ldo + col;
        if (EPI == 3) outF[idx] = tanhf(val);
        else          o1[idx] = f2bf(val);
      }
    }
  }
}

// ---------------------------------------------------------------------------
// 128^2 kernel for the batched GEMMs (len-skip / len-clamp), gld16 staging.
// EPI: 0 = split bf16 out; 1 = f32 out; 3 = tanh f32 out; 4 = bf16 out.
// ---------------------------------------------------------------------------
template<bool SPLIT, int EPI>
__global__ __launch_bounds__(256, 2) void gemm_kernel(
    const unsigned short* __restrict__ Ah, const unsigned short* __restrict__ Al,
    const unsigned short* __restrict__ Bh, const unsigned short* __restrict__ Bl,
    int K, int lda, int ldb,
    long long aStride, long long bStride, long long oStride,
    float* __restrict__ outF, unsigned short* __restrict__ o1,
    unsigned short* __restrict__ o2, int ldo,
    const int* __restrict__ lens, int lmode)
{
  constexpr int TILE = 128 * 64;  // bytes per staged tile
  __shared__ __align__(16) char smem[(SPLIT ? 4 : 2) * TILE];
  char* sAh = smem;
  char* sBh = smem + TILE;
  char* sAl = smem + (SPLIT ? 2 : 0) * TILE;
  char* sBl = smem + (SPLIT ? 3 : 0) * TILE;

  const int tid  = threadIdx.x;
  const int lane = tid & 63;
  const int wid  = tid >> 6;
  const int z    = blockIdx.z;

  int bx = blockIdx.x, by = blockIdx.y;
  if (gridDim.x == 8 && gridDim.y == 8){
    int o = bx + (by << 3);
    int k = o & 7, j = o >> 3;
    bx = ((k & 3) << 1) | (j & 1);  by = ((k >> 2) << 2) | (j >> 1);
  }
  const int m0 = by * 128;
  const int n0 = bx * 128;

  int Keff = K;
  if (lmode){
    const int len = lens[z];
    if (lmode == 1 && n0 >= len) return;       // output fully masked downstream
    if (lmode == 2){
      int kc = (len + 31) & ~31;
      Keff = kc < K ? kc : K;                  // P is exactly 0 beyond len
    }
  }

  const unsigned short* gAh = Ah + (size_t)z * aStride + (size_t)m0 * lda;
  const unsigned short* gBh = Bh + (size_t)z * bStride + (size_t)n0 * ldb;
  const unsigned short* gAl = SPLIT ? (Al + (size_t)z * aStride + (size_t)m0 * lda) : (const unsigned short*)0;
  const unsigned short* gBl = SPLIT ? (Bl + (size_t)z * bStride + (size_t)n0 * ldb) : (const unsigned short*)0;

  // gld16 staging plan: wave w covers rows 32w..32w+31 of the 128-row A and
  // B tiles.  Pre-swizzled source, linear LDS dest (rule 21).
  const int rS0 = (wid << 5) + (lane >> 2);
  const int rS1 = rS0 + 16;
  const int cS0 = ((lane & 3) ^ ((rS0 >> 1) & 3)) << 3;
  const int cS1 = ((lane & 3) ^ ((rS1 >> 1) & 3)) << 3;
  const int dS0 = (wid << 5) << 6;
  const int dS1 = dS0 + (16 << 6);
  const unsigned short* qAh0 = gAh + (size_t)rS0 * lda + cS0;
  const unsigned short* qAh1 = gAh + (size_t)rS1 * lda + cS1;
  const unsigned short* qBh0 = gBh + (size_t)rS0 * ldb + cS0;
  const unsigned short* qBh1 = gBh + (size_t)rS1 * ldb + cS1;
  const unsigned short* qAl0 = SPLIT ? (gAl + (size_t)rS0 * lda + cS0) : (const unsigned short*)0;
  const unsigned short* qAl1 = SPLIT ? (gAl + (size_t)rS1 * lda + cS1) : (const unsigned short*)0;
  const unsigned short* qBl0 = SPLIT ? (gBl + (size_t)rS0 * ldb + cS0) : (const unsigned short*)0;
  const unsigned short* qBl1 = SPLIT ? (gBl + (size_t)rS1 * ldb + cS1) : (const unsigned short*)0;

  f32x4 acc[4][4];
  #pragma unroll
  for (int m = 0; m < 4; m++)
    #pragma unroll
    for (int n = 0; n < 4; n++)
      acc[m][n] = (f32x4){0.f, 0.f, 0.f, 0.f};

  const int wr = (wid >> 1) * 64;
  const int wc = (wid & 1) * 64;
  const int fr = lane & 15;
  const int kb = lane >> 4;

  for (int k0 = 0; k0 < Keff; k0 += 32){
    __syncthreads();                      // WAR: all reads of prev tile done
    gld16(sAh + dS0, qAh0 + k0);
    gld16(sAh + dS1, qAh1 + k0);
    gld16(sBh + dS0, qBh0 + k0);
    gld16(sBh + dS1, qBh1 + k0);
    if (SPLIT){
      gld16(sAl + dS0, qAl0 + k0);
      gld16(sAl + dS1, qAl1 + k0);
      gld16(sBl + dS0, qBl0 + k0);
      gld16(sBl + dS1, qBl1 + k0);
    }
    __syncthreads();                      // drains vmcnt -> tile visible

    short8 ah[4], bh[4], al[4], bl[4];
    #pragma unroll
    for (int m = 0; m < 4; m++){
      int off = lds_off(wr + m * 16 + fr, kb);
      ah[m] = *(const short8*)(sAh + off);
      if (SPLIT) al[m] = *(const short8*)(sAl + off);
    }
    #pragma unroll
    for (int n = 0; n < 4; n++){
      int off = lds_off(wc + n * 16 + fr, kb);
      bh[n] = *(const short8*)(sBh + off);
      if (SPLIT) bl[n] = *(const short8*)(sBl + off);
    }
    #pragma unroll
    for (int m = 0; m < 4; m++)
      #pragma unroll
      for (int n = 0; n < 4; n++){
        acc[m][n] = __builtin_amdgcn_mfma_f32_16x16x32_bf16(ah[m], bh[n], acc[m][n], 0, 0, 0);
        if (SPLIT){
          acc[m][n] = __builtin_amdgcn_mfma_f32_16x16x32_bf16(ah[m], bl[n], acc[m][n], 0, 0, 0);
          acc[m][n] = __builtin_amdgcn_mfma_f32_16x16x32_bf16(al[m], bh[n], acc[m][n], 0, 0, 0);
        }
      }
  }

  const int rbase = (lane >> 4) * 2 * 2;
  const int cbase = lane & 15;
  #pragma unroll
  for (int m = 0; m < 4; m++){
    #pragma unroll
    for (int n = 0; n < 4; n++){
      f32x4 v = acc[m][n];
      int col = n0 + wc + n * 16 + cbase;
      #pragma unroll
      for (int j = 0; j < 4; j++){
        int row = m0 + wr + m * 16 + rbase + j;
        float val = v[j];
        size_t idx = (size_t)row * ldo + col;
        if (EPI == 0){
          unsigned short h = f2bf(val);
          o1[(size_t)z * oStride + idx] = h;
          o2[(size_t)z * oStride + idx] = f2bf(val - bf2f(h));
        } else if (EPI == 1){
          outF[(size_t)z * oStride + idx] = val;
        } else if (EPI == 4){
          o1[(size_t)z * oStride + idx] = f2bf(val);
        } else {
          outF[idx] = tanhf(val);
        }
      }
    }
  }
}

extern "C" void kernel_launch(void* const* d_in, const int* in_sizes, int n_in,
                              void* d_out, int out_size, void* d_ws, size_t ws_size,
                              hipStream_t stream){
  const float* input   = (const float*)d_in[0];
  const float* context = (const float*)d_in[1];
  const int*   lens    = (const int*)d_in[2];
  const float* Win     = (const float*)d_in[3];
  const float* Wout    = (const float*)d_in[4];
  float* attn  = (float*)d_out;
  float* align = attn + (size_t)BT * DIM;

  char* ws = (char*)d_ws;
  size_t off = 0;
  auto alloc = [&](size_t bytes) -> char* {
    char* p = ws + off; off += (bytes + 255) & ~(size_t)255; return p;
  };
  const size_t MTD = (size_t)BT * DIM;   // 8M elements
  unsigned short* in_hi = (unsigned short*)alloc(MTD * 2);
  unsigned short* in_lo = (unsigned short*)alloc(MTD * 2);
  unsigned short* cx_hi = (unsigned short*)alloc(MTD * 2);
  unsigned short* cx_lo = (unsigned short*)alloc(MTD * 2);
  unsigned short* wi_hi = (unsigned short*)alloc((size_t)DIM * DIM * 2);
  unsigned short* wi_lo = (unsigned short*)alloc((size_t)DIM * DIM * 2);
  unsigned short* ht_hi = (unsigned short*)alloc(MTD * 2);
  unsigned short* ht_lo = (unsigned short*)alloc(MTD * 2);
  unsigned short* cxT   = (unsigned short*)alloc(MTD * 2);
  unsigned short* c_hi  = (unsigned short*)alloc(MTD * 2);   // GEMM3 out (plain bf16)
  unsigned short* wo_hi = (unsigned short*)alloc((size_t)DIM * 2 * DIM * 2);
  unsigned short* p_bf  = cx_hi;   // alias: cx_hi dead after GEMM2
  if (off > ws_size) return;

  // prep: splits + W conversions + fused context split/transpose
  split_kernel<<<4096, 256, 0, stream>>>(input, in_hi, in_lo, (int)(MTD >> 2));
  split_kernel<<<1024, 256, 0, stream>>>(Win, wi_hi, wi_lo, (DIM * DIM) >> 2);
  cvt_kernel<<<2048, 256, 0, stream>>>(Wout, wo_hi, (DIM * 2 * DIM) >> 2);
  ctx_prep_kernel<<<dim3(16, 16, NBAT), dim3(64, 4), 0, stream>>>(context, cx_hi, cx_lo, cxT);

  // GEMM1: ht = input @ Win^T   (pipelined SM0 full split -- score path)
  gemm_pipe_kernel<0, 32, 1024, 0><<<dim3(8, 32), 512, 0, stream>>>(
      in_hi, in_lo, in_hi, in_lo, wi_hi, wi_lo, DIM, DIM,
      nullptr, ht_hi, ht_lo, DIM);
  // GEMM2: scores[b] = ht[b] @ ctx[b]^T  (split in, f32 out -> align region)
  gemm_kernel<true, 1><<<dim3(8, 8, NBAT), 256, 0, stream>>>(
      ht_hi, ht_lo, cx_hi, cx_lo, DIM, DIM, DIM,
      (long long)DIM * 1024, (long long)DIM * 1024, (long long)DIM * 1024,
      align, nullptr, nullptr, DIM, lens, 1);
  // masked softmax (in-place on align) + P bf16
  softmax_kernel<<<BT, 256, 0, stream>>>(align, p_bf, lens);
  // GEMM3: c[b] = P[b] @ ctxT[b]^T  (plain bf16 in, single bf16 out)
  gemm_kernel<false, 4><<<dim3(8, 8, NBAT), 256, 0, stream>>>(
      p_bf, nullptr, cxT, nullptr, DIM, DIM, DIM,
      (long long)DIM * 1024, (long long)DIM * 1024, (long long)1024 * 1024,
      nullptr, c_hi, nullptr, DIM, lens, 2);
  // GEMM4: attn = tanh([c | input] @ Wout^T)  (128x128 pipe, 3 blocks/CU,
  //        pure bf16, A split at k=1024 -- same math order, bits identical)
  gemm_pipe128_kernel<3, 64, 1024><<<dim3(8, 64), 256, 0, stream>>>(
      c_hi, in_hi, wo_hi, DIM, 2 * DIM,
      attn, nullptr, DIM);
}